// Round 1
// baseline (310.681 us; speedup 1.0000x reference)
//
#include <hip/hip_runtime.h>
#include <hip/hip_bf16.h>

#define NGRAPH 4096
#define MAXN 4096

typedef __attribute__((ext_vector_type(8))) short s16x8;
typedef __attribute__((ext_vector_type(4))) float f32x4;

__device__ inline short f2bf(float f) {
  unsigned u = __float_as_uint(f);
  unsigned r = u + 0x7fffu + ((u >> 16) & 1u);
  return (short)(r >> 16);
}

// Prepack W1 (256x128 fp32, row-major) into bf16 MFMA B-fragment order.
// Fragment f = kt*8 + ct (kt,ct in 0..7). Lane l supplies B[k][c] for
// k = kt*32 + (l>>4)*8 + e (e=0..7), c = ct*16 + (l&15).
__global__ void prepack_w1(const float* __restrict__ W1, s16x8* __restrict__ w1p) {
  int t = blockIdx.x * 256 + threadIdx.x;   // 4096 threads total
  int f = t >> 6, l = t & 63;
  int kt = f >> 3, ct = f & 7;
  int k0 = kt * 32 + ((l >> 4) * 8);
  int c  = ct * 16 + (l & 15);
  s16x8 v;
  #pragma unroll
  for (int e = 0; e < 8; ++e) v[e] = f2bf(W1[(k0 + e) * 128 + c]);
  w1p[f * 64 + l] = v;
}

__device__ inline long long getb(const void* b, int i, int is64) {
  if (is64) return ((const long long*)b)[i];
  return (long long)((const int*)b)[i];
}

__device__ inline int lowb(const void* b, int n, long long v, int is64) {
  int lo = 0, hi = n;
  while (lo < hi) {
    int mid = (lo + hi) >> 1;
    if (getb(b, mid, is64) < v) lo = mid + 1; else hi = mid;
  }
  return lo;
}

__device__ inline float fast_tanh(float v) {
  v = fminf(fmaxf(v, -15.f), 15.f);
  float e = __expf(2.f * v);
  return __fdividef(e - 1.f, e + 1.f);
}

__global__ __launch_bounds__(256, 2)
void attnpool(const float* __restrict__ x, const void* __restrict__ batch,
              const float* __restrict__ b1, const float* __restrict__ W2,
              const float* __restrict__ b2p, const s16x8* __restrict__ w1p,
              float* __restrict__ pooled, float* __restrict__ wout, int N)
{
  __shared__ float spart[2][MAXN];
  __shared__ float sred[8];

  const int g = blockIdx.x;
  const int tid = threadIdx.x;
  const int w = tid >> 6, l = tid & 63;
  const int colhalf = w & 1;            // waves 0,2 -> cols 0..63; waves 1,3 -> 64..127
  const int l15 = l & 15, lg = l >> 4;

  // Detect whether batch was materialized as int64 or int32:
  // probe an odd int32 index; for int64 (values<2^31) it's a zero high word,
  // for int32 it's a near-last sorted graph id (=4095 w.p. 1).
  int probe = ((N & 1) == 0) ? (N - 1) : (N - 2);
  const int is64 = (((const int*)batch)[probe] == 0) ? 1 : 0;

  const int s = lowb(batch, N, (long long)g, is64);
  const int e = lowb(batch, N, (long long)(g + 1), is64);
  const int cnt = e - s;

  // B fragments (this wave's 64 columns x K=256) held in registers: 32 frags.
  s16x8 bf[4][8];
  #pragma unroll
  for (int ctl = 0; ctl < 4; ++ctl) {
    #pragma unroll
    for (int kt = 0; kt < 8; ++kt)
      bf[ctl][kt] = w1p[(kt * 8 + colhalf * 4 + ctl) * 64 + l];
  }

  float b1v[4], w2v[4];
  #pragma unroll
  for (int ctl = 0; ctl < 4; ++ctl) {
    int c = colhalf * 64 + ctl * 16 + l15;
    b1v[ctl] = b1[c];
    w2v[ctl] = W2[c];
  }
  const float b2s = b2p[0];

  // ---- Phase 1: gate scores via MFMA (16-node tiles; wave pair per tile) ----
  const int tiles = (cnt + 15) >> 4;
  for (int t = (w >> 1); t < tiles; t += 2) {
    const int tb = t * 16;
    int row = s + tb + l15;
    if (row >= N) row = N - 1;          // pad rows: garbage, discarded below
    const float* xp = x + (size_t)row * 256 + lg * 8;
    f32x4 acc0 = {0.f,0.f,0.f,0.f}, acc1 = {0.f,0.f,0.f,0.f};
    f32x4 acc2 = {0.f,0.f,0.f,0.f}, acc3 = {0.f,0.f,0.f,0.f};
    #pragma unroll
    for (int kt = 0; kt < 8; ++kt) {
      float4 xa = *(const float4*)(xp + kt * 32);
      float4 xb = *(const float4*)(xp + kt * 32 + 4);
      s16x8 a;
      a[0] = f2bf(xa.x); a[1] = f2bf(xa.y); a[2] = f2bf(xa.z); a[3] = f2bf(xa.w);
      a[4] = f2bf(xb.x); a[5] = f2bf(xb.y); a[6] = f2bf(xb.z); a[7] = f2bf(xb.w);
      acc0 = __builtin_amdgcn_mfma_f32_16x16x32_bf16(a, bf[0][kt], acc0, 0, 0, 0);
      acc1 = __builtin_amdgcn_mfma_f32_16x16x32_bf16(a, bf[1][kt], acc1, 0, 0, 0);
      acc2 = __builtin_amdgcn_mfma_f32_16x16x32_bf16(a, bf[2][kt], acc2, 0, 0, 0);
      acc3 = __builtin_amdgcn_mfma_f32_16x16x32_bf16(a, bf[3][kt], acc3, 0, 0, 0);
    }
    // Epilogue: h = tanh(acc + b1), partial score = sum h*W2 over this wave's cols.
    // D layout: row = 4*(l>>4)+r (node in tile), col = l&15.
    float part[4];
    #pragma unroll
    for (int r = 0; r < 4; ++r) part[r] = colhalf ? 0.f : b2s;
    #pragma unroll
    for (int r = 0; r < 4; ++r) {
      part[r] += fast_tanh(acc0[r] + b1v[0]) * w2v[0];
      part[r] += fast_tanh(acc1[r] + b1v[1]) * w2v[1];
      part[r] += fast_tanh(acc2[r] + b1v[2]) * w2v[2];
      part[r] += fast_tanh(acc3[r] + b1v[3]) * w2v[3];
    }
    #pragma unroll
    for (int m = 1; m <= 8; m <<= 1) {
      #pragma unroll
      for (int r = 0; r < 4; ++r) part[r] += __shfl_xor(part[r], m, 64);
    }
    if (l15 == 0) {
      #pragma unroll
      for (int r = 0; r < 4; ++r) {
        int nl = tb + lg * 4 + r;
        if (nl < cnt) spart[colhalf][nl] = part[r];
      }
    }
  }
  __syncthreads();

  if (cnt > 0) {
    // ---- Phase 2: segment softmax (deterministic, no atomics) ----
    float lmax = -1e30f;
    for (int i = tid; i < cnt; i += 256) {
      float sc = spart[0][i] + spart[1][i];
      spart[0][i] = sc;
      lmax = fmaxf(lmax, sc);
    }
    #pragma unroll
    for (int m = 1; m <= 32; m <<= 1) lmax = fmaxf(lmax, __shfl_xor(lmax, m, 64));
    if (l == 0) sred[w] = lmax;
    __syncthreads();
    const float gmax = fmaxf(fmaxf(sred[0], sred[1]), fmaxf(sred[2], sred[3]));
    float lsum = 0.f;
    for (int i = tid; i < cnt; i += 256) {
      float ev = __expf(spart[0][i] - gmax);
      spart[0][i] = ev;
      lsum += ev;
    }
    #pragma unroll
    for (int m = 1; m <= 32; m <<= 1) lsum += __shfl_xor(lsum, m, 64);
    if (l == 0) sred[4 + w] = lsum;
    __syncthreads();
    const float inv = 1.f / (sred[4] + sred[5] + sred[6] + sred[7]);
    for (int i = tid; i < cnt; i += 256) {
      float wt = spart[0][i] * inv;
      spart[0][i] = wt;
      wout[s + i] = wt;
    }
    __syncthreads();

    // ---- Phase 3: pooled[g][col] = sum_n w_n * x[s+n][col], col = tid ----
    float pacc = 0.f;
    const float* xg = x + (size_t)s * 256 + tid;
    int n = 0;
    for (; n + 4 <= cnt; n += 4) {
      float w0 = spart[0][n+0], w1f = spart[0][n+1];
      float w2f = spart[0][n+2], w3f = spart[0][n+3];
      pacc += w0  * xg[(size_t)(n+0) * 256];
      pacc += w1f * xg[(size_t)(n+1) * 256];
      pacc += w2f * xg[(size_t)(n+2) * 256];
      pacc += w3f * xg[(size_t)(n+3) * 256];
    }
    for (; n < cnt; ++n) pacc += spart[0][n] * xg[(size_t)n * 256];
    pooled[(size_t)g * 256 + tid] = pacc;
  } else {
    pooled[(size_t)g * 256 + tid] = 0.f;   // empty segment -> zeros (matches ref guard)
  }
}

extern "C" void kernel_launch(void* const* d_in, const int* in_sizes, int n_in,
                              void* d_out, int out_size, void* d_ws, size_t ws_size,
                              hipStream_t stream) {
  const float* x     = (const float*)d_in[0];
  const void*  batch = d_in[1];
  const float* W1    = (const float*)d_in[2];
  const float* b1    = (const float*)d_in[3];
  const float* W2    = (const float*)d_in[4];
  const float* b2    = (const float*)d_in[5];
  const int N = in_sizes[0] / 256;

  float* pooled = (float*)d_out;
  float* wout   = (float*)d_out + (size_t)NGRAPH * 256;
  s16x8* w1p    = (s16x8*)d_ws;   // 64 KB

  prepack_w1<<<16, 256, 0, stream>>>(W1, w1p);
  attnpool<<<NGRAPH, 256, 0, stream>>>(x, batch, b1, W2, b2, w1p, pooled, wout, N);
}